// Round 11
// baseline (184.719 us; speedup 1.0000x reference)
//
#include <hip/hip_runtime.h>
#include <hip/hip_bf16.h>

typedef __attribute__((ext_vector_type(8))) short s8v;    // 8 bf16
typedef __attribute__((ext_vector_type(4))) short s4v;    // 4 bf16
typedef __attribute__((ext_vector_type(4))) float f4v;    // 4 fp32

__device__ __forceinline__ void g2lds16(const void* g, void* l) {
  __builtin_amdgcn_global_load_lds(
      (__attribute__((address_space(1))) void*)(g),
      (__attribute__((address_space(3))) void*)(l), 16, 0, 0);
}

__device__ __forceinline__ short f2bf(float f) {
  __hip_bfloat16 h = __float2bfloat16(f);
  return *reinterpret_cast<short*>(&h);
}

// ---------------- K0: fused x->bf16 cvt  +  W transpose->bf16 ----------------
__global__ void k_prep(const float* __restrict__ x, const float* __restrict__ W,
                       __hip_bfloat16* __restrict__ xb, __hip_bfloat16* __restrict__ Wt) {
  int bx = blockIdx.x;
  if (bx < 4096) {
    int i = (bx * 256 + threadIdx.x) * 4;
    float4 v = *(const float4*)(x + i);
    __hip_bfloat16 o[4] = {__float2bfloat16(v.x), __float2bfloat16(v.y),
                           __float2bfloat16(v.z), __float2bfloat16(v.w)};
    *(uint2*)(xb + i) = *(const uint2*)(o);
  } else {
    __shared__ float tile[32][33];
    int r = bx - 4096;            // 0..3071 = 32 x 96
    int rt = r / 96;              // over 1024/32
    int ct = r - rt * 96;         // over 3072/32
    int c0 = ct * 32, r0 = rt * 32;
    int tr = threadIdx.x >> 5, tc = threadIdx.x & 31;
#pragma unroll
    for (int i = 0; i < 32; i += 8)
      tile[tr + i][tc] = W[(size_t)(r0 + tr + i) * 3072 + c0 + tc];
    __syncthreads();
#pragma unroll
    for (int i = 0; i < 32; i += 8)
      Wt[(size_t)(c0 + tr + i) * 1024 + r0 + tc] = __float2bfloat16(tile[tc][tr + i]);
  }
}

// ---------------- K1: GEMM + fused QKV scatter epilogue ----------------
// (unchanged known-good: 128^2 tile, BK=32, 4 waves, 768 blocks, ~57.5us.
//  Attention scale 0.125*log2e folded into Q at the epilogue.)
__global__ __launch_bounds__(256) void k_gemm(const __hip_bfloat16* __restrict__ A,
                                              const __hip_bfloat16* __restrict__ Bt,
                                              const float* __restrict__ bias,
                                              __hip_bfloat16* __restrict__ Q,
                                              __hip_bfloat16* __restrict__ K,
                                              __hip_bfloat16* __restrict__ Vt) {
  __shared__ __align__(16) __hip_bfloat16 As[2][128 * 32];
  __shared__ __align__(16) __hip_bfloat16 Bs[2][128 * 32];
  const int tid = threadIdx.x;
  const int lane = tid & 63, wave = tid >> 6;
  const int m0 = blockIdx.y * 128, n0 = blockIdx.x * 128;
  const int wm = (wave & 1) * 64, wn = (wave >> 1) * 64;
  const int lrow = lane & 15;
  const int quad = lane >> 4;

  f4v acc[4][4] = {};

  auto stage = [&](int k0, int kb) {
#pragma unroll
    for (int c = 0; c < 2; ++c) {
      int e = c * 2048 + tid * 8;             // element idx in 128x32 tile
      int row = e >> 5;
      int slot = (e & 31) >> 3;               // 0..3 (8-elem slots)
      int src = k0 + ((slot ^ ((row >> 1) & 3)) << 3);
      g2lds16(A + (size_t)(m0 + row) * 1024 + src, &As[kb][e]);
      g2lds16(Bt + (size_t)(n0 + row) * 1024 + src, &Bs[kb][e]);
    }
  };

  const int swz = (quad ^ ((lrow >> 1) & 3)) * 8;  // swizzled k-slot for frag reads

  stage(0, 0);
  for (int it = 0; it < 32; ++it) {
    __syncthreads();                    // drains stage(it) (issued one iter ago)
    if (it < 31) stage((it + 1) * 32, (it + 1) & 1);
    const __hip_bfloat16* Ab = As[it & 1];
    const __hip_bfloat16* Bb = Bs[it & 1];
    s8v af[4], bfr[4];
#pragma unroll
    for (int mi = 0; mi < 4; ++mi) af[mi] = *(const s8v*)(Ab + (wm + mi * 16 + lrow) * 32 + swz);
#pragma unroll
    for (int ni = 0; ni < 4; ++ni) bfr[ni] = *(const s8v*)(Bb + (wn + ni * 16 + lrow) * 32 + swz);
#pragma unroll
    for (int mi = 0; mi < 4; ++mi)
#pragma unroll
      for (int ni = 0; ni < 4; ++ni)
        acc[mi][ni] = __builtin_amdgcn_mfma_f32_16x16x32_bf16(af[mi], bfr[ni], acc[mi][ni], 0, 0, 0);
  }

  // epilogue: per-row destination decode, d-packed 8B stores for Q/K
  const int cw = n0 + wn;            // multiple of 64 -> c10 wave-uniform
  const int c10 = cw >> 10;          // 0..2
  const int d0 = (cw & 1023) >> 4;   // multiple of 4
  const int h = lrow;
  float bv[4];
#pragma unroll
  for (int ni = 0; ni < 4; ++ni) bv[ni] = bias[cw + ni * 16 + lrow];

#pragma unroll
  for (int mi = 0; mi < 4; ++mi) {
    int rbase = m0 + wm + mi * 16 + quad * 4;
#pragma unroll
    for (int reg = 0; reg < 4; ++reg) {
      int rr = rbase + reg;
      int u = 3 * rr + c10;
      int s = u >> 12;
      int b = (u >> 11) & 1;
      int t = u & 2047;
      if (s < 2) {
        __hip_bfloat16* dst = (s == 0) ? Q : K;
        // Q carries the attention scale: 0.125 * log2(e)
        const float qs = (s == 0) ? 0.18033688011112042f : 1.0f;
        s4v pk;
#pragma unroll
        for (int ni = 0; ni < 4; ++ni) pk[ni] = f2bf((acc[mi][ni][reg] + bv[ni]) * qs);
        *(s4v*)(dst + ((size_t)(b * 16 + h) * 2048 + t) * 64 + d0) = pk;
      } else {
#pragma unroll
        for (int ni = 0; ni < 4; ++ni)
          Vt[((size_t)(b * 16 + h) * 64 + d0 + ni) * 2048 + t] =
              __float2bfloat16(acc[mi][ni][reg] + bv[ni]);
      }
    }
  }
}

// ---------------- K2: causal flash attention, KVBLK=128 ----------------
// Round-10 structure with the KV tile doubled 64->128: halves the count of
// barriers, stage-issue blocks, shuffle reductions, defer-max checks and
// loop iterations while keeping per-kv compute density identical.
// LDS 2 x 32KB (K [128][128B] + V [64][256B]) = 64KB -> 2 blocks/CU.
// Fragment algebra generalizes: S[8] (kv = nt*16+q*4+r), PV sc=0..7 with
// V row stride 256B / 16 swizzle slots (XOR lx bijective in 0..15).
// Tail: JT=(qb+2)>>1 tiles; last tile's rows beyond tg masked to -1e30
// (max row 2047, never OOB). Heavy-first 1024-block schedule retained.
__global__ __launch_bounds__(256, 2) void k_attn(const __hip_bfloat16* __restrict__ Q,
                                                 const __hip_bfloat16* __restrict__ K,
                                                 const __hip_bfloat16* __restrict__ Vt,
                                                 float* __restrict__ out) {
  __shared__ __align__(16) char lds[2][32768];  // per buf: K 16KB | V 16KB

  const int tid = threadIdx.x;
  const int lane = tid & 63, w = tid >> 6;
  const int l = lane & 15, q = lane >> 4, lx = l & 7;

  const int bid = blockIdx.x;           // 1024 blocks
  const int xcd = bid & 7;
  const int idx = bid >> 3;             // 0..127
  const int bh = xcd + 8 * (idx & 3);   // 4 bh per XCD -> 2MB K+V in its L2
  const int qb = 31 - (idx >> 2);       // heavy blocks first
  const int JT = (qb + 2) >> 1;         // 128-wide KV tiles to sweep

  const char* Kb = (const char*)(K + (size_t)bh * 131072);
  const char* Vb = (const char*)(Vt + (size_t)bh * 131072);
  const __hip_bfloat16* Qp = Q + (size_t)bh * 131072 + (size_t)qb * 4096;

  // Q fragment (load once): B[n=t][k], t = qb*64 + w*16 + l
  s8v Qf[2];
#pragma unroll
  for (int kh = 0; kh < 2; ++kh)
    Qf[kh] = *(const s8v*)(Qp + (size_t)(w * 16 + l) * 64 + kh * 32 + q * 8);

  f4v O[4] = {};
  float m = -INFINITY, lsum = 0.f;
  const int tg = qb * 64 + w * 16 + l;          // this lane's global Q row

  auto stage = [&](int jt, char* buf) {
#pragma unroll
    for (int c = 0; c < 8; ++c) {
      int chunk = w * 8 + c;            // 0..31
      int ls = chunk * 64 + lane;       // 16B-slot index 0..2047
      if (chunk < 16) {                 // K tile: LDS[row][kb] = K[row][kb ^ (row&7)]
        int row = ls >> 3, kb = ls & 7;
        g2lds16(Kb + (size_t)jt * 16384 + row * 128 + ((kb ^ (row & 7)) << 4),
                buf + ls * 16);
      } else {                          // V tile: LDS[d][kb] = V^T[d][kb ^ (d&7)], 16 slots
        int ls2 = ls - 1024;
        int d = ls2 >> 4, kb = ls2 & 15;
        g2lds16(Vb + (size_t)d * 4096 + (size_t)jt * 256 + ((kb ^ (d & 7)) << 4),
                buf + 16384 + ls2 * 16);
      }
    }
  };

  stage(0, lds[0]);
  __syncthreads();

  for (int jt = 0; jt < JT; ++jt) {
    const char* Kl = lds[jt & 1];
    const char* Vl = Kl + 16384;
    if (jt + 1 < JT) stage(jt + 1, lds[(jt + 1) & 1]);

    // S^T: A = K rows (m = kv_local), B = Q (n = t); S already log2-scaled
    f4v S[8];
    __builtin_amdgcn_s_setprio(1);
#pragma unroll
    for (int nt = 0; nt < 8; ++nt) {
      const char* rowp = Kl + (nt * 16 + l) * 128;
      s8v k0 = *(const s8v*)(rowp + ((q ^ lx) << 4));
      s8v k1 = *(const s8v*)(rowp + (((4 + q) ^ lx) << 4));
      f4v z = {0.f, 0.f, 0.f, 0.f};
      z = __builtin_amdgcn_mfma_f32_16x16x32_bf16(k0, Qf[0], z, 0, 0, 0);
      z = __builtin_amdgcn_mfma_f32_16x16x32_bf16(k1, Qf[1], z, 0, 0, 0);
      S[nt] = z;
    }
    __builtin_amdgcn_s_setprio(0);

    if (jt == JT - 1) {                 // mask causal diag + invalid upper rows
#pragma unroll
      for (int nt = 0; nt < 8; ++nt)
#pragma unroll
        for (int r = 0; r < 4; ++r)
          if (jt * 128 + nt * 16 + q * 4 + r > tg) S[nt][r] = -1e30f;
    }

    // depth-5 max tree over 32 values
    float mnt[8];
#pragma unroll
    for (int nt = 0; nt < 8; ++nt)
      mnt[nt] = fmaxf(fmaxf(S[nt][0], S[nt][1]), fmaxf(S[nt][2], S[nt][3]));
    float m01 = fmaxf(mnt[0], mnt[1]), m23 = fmaxf(mnt[2], mnt[3]);
    float m45 = fmaxf(mnt[4], mnt[5]), m67 = fmaxf(mnt[6], mnt[7]);
    float mx = fmaxf(fmaxf(m01, m23), fmaxf(m45, m67));
    mx = fmaxf(mx, __shfl_xor(mx, 16));
    mx = fmaxf(mx, __shfl_xor(mx, 32));

    // T13 defer-max: rescale only when the max grew by > 8 (wave-uniform)
    if (!__all(mx - m <= 8.f)) {
      float mn = fmaxf(m, mx);
      float alpha = exp2f(m - mn);
      m = mn;
      lsum *= alpha;
#pragma unroll
      for (int dt = 0; dt < 4; ++dt) O[dt] *= alpha;
    }

    // exp pass with per-nt partial sums (tree reduction)
    float rsp[8];
    s4v Pf[8];
#pragma unroll
    for (int nt = 0; nt < 8; ++nt) {
      float e0 = exp2f(S[nt][0] - m);
      float e1 = exp2f(S[nt][1] - m);
      float e2 = exp2f(S[nt][2] - m);
      float e3 = exp2f(S[nt][3] - m);
      Pf[nt][0] = f2bf(e0);
      Pf[nt][1] = f2bf(e1);
      Pf[nt][2] = f2bf(e2);
      Pf[nt][3] = f2bf(e3);
      rsp[nt] = (e0 + e1) + (e2 + e3);
    }
    float rs = ((rsp[0] + rsp[1]) + (rsp[2] + rsp[3])) +
               ((rsp[4] + rsp[5]) + (rsp[6] + rsp[7]));
    rs += __shfl_xor(rs, 16);
    rs += __shfl_xor(rs, 32);
    lsum += rs;

    // PV: A = V^T rows (m = d), B = P (n = t, k = kv in C-layout regs)
    __builtin_amdgcn_s_setprio(1);
#pragma unroll
    for (int sc = 0; sc < 8; ++sc) {
      int so = ((sc * 2 + (q >> 1)) ^ lx) * 16 + (q & 1) * 8;
#pragma unroll
      for (int dt = 0; dt < 4; ++dt) {
        s4v vv = *(const s4v*)(Vl + (dt * 16 + l) * 256 + so);
        O[dt] = __builtin_amdgcn_mfma_f32_16x16x16bf16_1k(vv, Pf[sc], O[dt], 0, 0, 0);
      }
    }
    __builtin_amdgcn_s_setprio(0);
    __syncthreads();  // staging of jt+1 drained; all waves done with buf (jt&1)
  }

  // epilogue: lane holds row t = tg, cols d = dt*16 + q*4 + r  -> float4 stores
  float inv = 1.f / lsum;
  int b = bh >> 4, h = bh & 15;
  float* ob = out + ((size_t)b * 2048 + tg) * 1024 + h * 64;
#pragma unroll
  for (int dt = 0; dt < 4; ++dt) {
    f4v val = O[dt] * inv;
    *(f4v*)(ob + dt * 16 + q * 4) = val;
  }
}

extern "C" void kernel_launch(void* const* d_in, const int* in_sizes, int n_in,
                              void* d_out, int out_size, void* d_ws, size_t ws_size,
                              hipStream_t stream) {
  const float* x = (const float*)d_in[0];     // [2,2048,1024]
  const float* W = (const float*)d_in[1];     // [1024,3072]
  const float* bias = (const float*)d_in[2];  // [3072]
  float* out = (float*)d_out;                 // [2,2048,1024]

  char* ws = (char*)d_ws;
  __hip_bfloat16* xb = (__hip_bfloat16*)ws;                    // 8,388,608 B
  __hip_bfloat16* Wt = (__hip_bfloat16*)(ws + 8388608);        // 6,291,456 B
  __hip_bfloat16* Qg = (__hip_bfloat16*)(ws + 14680064);       // 8,388,608 B
  __hip_bfloat16* Kg = (__hip_bfloat16*)(ws + 23068672);       // 8,388,608 B
  __hip_bfloat16* Vt = (__hip_bfloat16*)(ws + 31457280);       // 8,388,608 B

  k_prep<<<7168, 256, 0, stream>>>(x, W, xb, Wt);
  k_gemm<<<dim3(24, 32), 256, 0, stream>>>(xb, Wt, bias, Qg, Kg, Vt);
  k_attn<<<1024, 256, 0, stream>>>(Qg, Kg, Vt, out);
}

// Round 12
// 175.406 us; speedup vs baseline: 1.0531x; 1.0531x over previous
//
#include <hip/hip_runtime.h>
#include <hip/hip_bf16.h>

typedef __attribute__((ext_vector_type(8))) short s8v;    // 8 bf16
typedef __attribute__((ext_vector_type(4))) short s4v;    // 4 bf16
typedef __attribute__((ext_vector_type(4))) float f4v;    // 4 fp32

__device__ __forceinline__ void g2lds16(const void* g, void* l) {
  __builtin_amdgcn_global_load_lds(
      (__attribute__((address_space(1))) void*)(g),
      (__attribute__((address_space(3))) void*)(l), 16, 0, 0);
}

__device__ __forceinline__ short f2bf(float f) {
  __hip_bfloat16 h = __float2bfloat16(f);
  return *reinterpret_cast<short*>(&h);
}

// ---------------- K0: fused x->bf16 cvt  +  W transpose->bf16 ----------------
__global__ void k_prep(const float* __restrict__ x, const float* __restrict__ W,
                       __hip_bfloat16* __restrict__ xb, __hip_bfloat16* __restrict__ Wt) {
  int bx = blockIdx.x;
  if (bx < 4096) {
    int i = (bx * 256 + threadIdx.x) * 4;
    float4 v = *(const float4*)(x + i);
    __hip_bfloat16 o[4] = {__float2bfloat16(v.x), __float2bfloat16(v.y),
                           __float2bfloat16(v.z), __float2bfloat16(v.w)};
    *(uint2*)(xb + i) = *(const uint2*)(o);
  } else {
    __shared__ float tile[32][33];
    int r = bx - 4096;            // 0..3071 = 32 x 96
    int rt = r / 96;              // over 1024/32
    int ct = r - rt * 96;         // over 3072/32
    int c0 = ct * 32, r0 = rt * 32;
    int tr = threadIdx.x >> 5, tc = threadIdx.x & 31;
#pragma unroll
    for (int i = 0; i < 32; i += 8)
      tile[tr + i][tc] = W[(size_t)(r0 + tr + i) * 3072 + c0 + tc];
    __syncthreads();
#pragma unroll
    for (int i = 0; i < 32; i += 8)
      Wt[(size_t)(c0 + tr + i) * 1024 + r0 + tc] = __float2bfloat16(tile[tc][tr + i]);
  }
}

// ---------------- K1: GEMM + fused QKV scatter epilogue ----------------
// (unchanged known-good: 128^2 tile, BK=32, 4 waves, 768 blocks, ~57.5us.
//  Attention scale 0.125*log2e folded into Q at the epilogue.)
__global__ __launch_bounds__(256) void k_gemm(const __hip_bfloat16* __restrict__ A,
                                              const __hip_bfloat16* __restrict__ Bt,
                                              const float* __restrict__ bias,
                                              __hip_bfloat16* __restrict__ Q,
                                              __hip_bfloat16* __restrict__ K,
                                              __hip_bfloat16* __restrict__ Vt) {
  __shared__ __align__(16) __hip_bfloat16 As[2][128 * 32];
  __shared__ __align__(16) __hip_bfloat16 Bs[2][128 * 32];
  const int tid = threadIdx.x;
  const int lane = tid & 63, wave = tid >> 6;
  const int m0 = blockIdx.y * 128, n0 = blockIdx.x * 128;
  const int wm = (wave & 1) * 64, wn = (wave >> 1) * 64;
  const int lrow = lane & 15;
  const int quad = lane >> 4;

  f4v acc[4][4] = {};

  auto stage = [&](int k0, int kb) {
#pragma unroll
    for (int c = 0; c < 2; ++c) {
      int e = c * 2048 + tid * 8;             // element idx in 128x32 tile
      int row = e >> 5;
      int slot = (e & 31) >> 3;               // 0..3 (8-elem slots)
      int src = k0 + ((slot ^ ((row >> 1) & 3)) << 3);
      g2lds16(A + (size_t)(m0 + row) * 1024 + src, &As[kb][e]);
      g2lds16(Bt + (size_t)(n0 + row) * 1024 + src, &Bs[kb][e]);
    }
  };

  const int swz = (quad ^ ((lrow >> 1) & 3)) * 8;  // swizzled k-slot for frag reads

  stage(0, 0);
  for (int it = 0; it < 32; ++it) {
    __syncthreads();                    // drains stage(it) (issued one iter ago)
    if (it < 31) stage((it + 1) * 32, (it + 1) & 1);
    const __hip_bfloat16* Ab = As[it & 1];
    const __hip_bfloat16* Bb = Bs[it & 1];
    s8v af[4], bfr[4];
#pragma unroll
    for (int mi = 0; mi < 4; ++mi) af[mi] = *(const s8v*)(Ab + (wm + mi * 16 + lrow) * 32 + swz);
#pragma unroll
    for (int ni = 0; ni < 4; ++ni) bfr[ni] = *(const s8v*)(Bb + (wn + ni * 16 + lrow) * 32 + swz);
#pragma unroll
    for (int mi = 0; mi < 4; ++mi)
#pragma unroll
      for (int ni = 0; ni < 4; ++ni)
        acc[mi][ni] = __builtin_amdgcn_mfma_f32_16x16x32_bf16(af[mi], bfr[ni], acc[mi][ni], 0, 0, 0);
  }

  // epilogue: per-row destination decode, d-packed 8B stores for Q/K
  const int cw = n0 + wn;            // multiple of 64 -> c10 wave-uniform
  const int c10 = cw >> 10;          // 0..2
  const int d0 = (cw & 1023) >> 4;   // multiple of 4
  const int h = lrow;
  float bv[4];
#pragma unroll
  for (int ni = 0; ni < 4; ++ni) bv[ni] = bias[cw + ni * 16 + lrow];

#pragma unroll
  for (int mi = 0; mi < 4; ++mi) {
    int rbase = m0 + wm + mi * 16 + quad * 4;
#pragma unroll
    for (int reg = 0; reg < 4; ++reg) {
      int rr = rbase + reg;
      int u = 3 * rr + c10;
      int s = u >> 12;
      int b = (u >> 11) & 1;
      int t = u & 2047;
      if (s < 2) {
        __hip_bfloat16* dst = (s == 0) ? Q : K;
        // Q carries the attention scale: 0.125 * log2(e)
        const float qs = (s == 0) ? 0.18033688011112042f : 1.0f;
        s4v pk;
#pragma unroll
        for (int ni = 0; ni < 4; ++ni) pk[ni] = f2bf((acc[mi][ni][reg] + bv[ni]) * qs);
        *(s4v*)(dst + ((size_t)(b * 16 + h) * 2048 + t) * 64 + d0) = pk;
      } else {
#pragma unroll
        for (int ni = 0; ni < 4; ++ni)
          Vt[((size_t)(b * 16 + h) * 64 + d0 + ni) * 2048 + t] =
              __float2bfloat16(acc[mi][ni][reg] + bv[ni]);
      }
    }
  }
}

// ---------------- K2: causal flash attention ----------------
// Round-4 body (best measured), ONE change: the final (causal-masked) KV tile
// is PEELED out of the main loop. Main loop body loses the per-iter mask
// compare, the stage guard, and the last barrier; tail tile masks
// unconditionally and stages nothing. Identical FP sequence per tile.
__global__ __launch_bounds__(256, 3) void k_attn(const __hip_bfloat16* __restrict__ Q,
                                                 const __hip_bfloat16* __restrict__ K,
                                                 const __hip_bfloat16* __restrict__ Vt,
                                                 float* __restrict__ out) {
  __shared__ __align__(16) char lds[2][16384];  // per buf: K tile 8KB | V tile 8KB

  const int tid = threadIdx.x;
  const int lane = tid & 63, w = tid >> 6;
  const int l = lane & 15, q = lane >> 4, lx = l & 7;

  const int bid = blockIdx.x;           // 1024 blocks
  const int xcd = bid & 7;
  const int idx = bid >> 3;             // 0..127
  const int bh = xcd + 8 * (idx & 3);   // 4 bh per XCD -> 2MB K+V in its L2
  const int qb = 31 - (idx >> 2);       // heavy blocks first; tiles 0..qb

  const char* Kb = (const char*)(K + (size_t)bh * 131072);
  const char* Vb = (const char*)(Vt + (size_t)bh * 131072);
  const __hip_bfloat16* Qp = Q + (size_t)bh * 131072 + (size_t)qb * 4096;

  // Q fragment (load once): B[n=t][k], t = qb*64 + w*16 + l
  s8v Qf[2];
#pragma unroll
  for (int kh = 0; kh < 2; ++kh)
    Qf[kh] = *(const s8v*)(Qp + (size_t)(w * 16 + l) * 64 + kh * 32 + q * 8);

  f4v O[4] = {};
  float m = -INFINITY, lsum = 0.f;
  const int tg = qb * 64 + w * 16 + l;          // this lane's global Q row

  auto stage = [&](int j, char* buf) {
#pragma unroll
    for (int c = 0; c < 4; ++c) {
      int chunk = w * 4 + c;            // 0..15
      int ls = chunk * 64 + lane;       // 16B-slot index
      if (chunk < 8) {                  // K tile: LDS[row][kb] = K[row][kb ^ (row&7)]
        int row = ls >> 3, kb = ls & 7;
        g2lds16(Kb + (size_t)j * 8192 + row * 128 + ((kb ^ (row & 7)) << 4),
                buf + ls * 16);
      } else {                          // V tile: LDS[d][kb] = V^T[d][kb ^ (d&7)]
        int ls2 = ls - 512;
        int d = ls2 >> 3, kb = ls2 & 7;
        g2lds16(Vb + (size_t)d * 4096 + (size_t)j * 128 + ((kb ^ (d & 7)) << 4),
                buf + 8192 + ls2 * 16);
      }
    }
  };

  // per-tile compute, shared by main loop (MASK=false) and peeled tail
  auto tile_body = [&](const char* Kl, const char* Vl, int j, bool domask) {
    // S^T: A = K rows (m = s_local), B = Q (n = t); S already log2-scaled
    f4v S[4];
#pragma unroll
    for (int nt = 0; nt < 4; ++nt) {
      const char* rowp = Kl + (nt * 16 + l) * 128;
      s8v k0 = *(const s8v*)(rowp + ((q ^ lx) << 4));
      s8v k1 = *(const s8v*)(rowp + (((4 + q) ^ lx) << 4));
      f4v z = {0.f, 0.f, 0.f, 0.f};
      z = __builtin_amdgcn_mfma_f32_16x16x32_bf16(k0, Qf[0], z, 0, 0, 0);
      z = __builtin_amdgcn_mfma_f32_16x16x32_bf16(k1, Qf[1], z, 0, 0, 0);
      S[nt] = z;
    }

    if (domask) {
#pragma unroll
      for (int nt = 0; nt < 4; ++nt)
#pragma unroll
        for (int r = 0; r < 4; ++r)
          if (j * 64 + nt * 16 + q * 4 + r > tg) S[nt][r] = -1e30f;
    }

    float mx = S[0][0];
#pragma unroll
    for (int nt = 0; nt < 4; ++nt)
#pragma unroll
      for (int r = 0; r < 4; ++r) mx = fmaxf(mx, S[nt][r]);
    mx = fmaxf(mx, __shfl_xor(mx, 16));
    mx = fmaxf(mx, __shfl_xor(mx, 32));

    // T13 defer-max: rescale only when the max grew by > 8 (wave-uniform)
    if (!__all(mx - m <= 8.f)) {
      float mn = fmaxf(m, mx);
      float alpha = exp2f(m - mn);
      m = mn;
      lsum *= alpha;
#pragma unroll
      for (int dt = 0; dt < 4; ++dt) O[dt] *= alpha;
    }

    float rs = 0.f;
    s4v Pf[4];
#pragma unroll
    for (int nt = 0; nt < 4; ++nt)
#pragma unroll
      for (int r = 0; r < 4; ++r) {
        float e = exp2f(S[nt][r] - m);
        rs += e;
        Pf[nt][r] = f2bf(e);
      }
    rs += __shfl_xor(rs, 16);
    rs += __shfl_xor(rs, 32);
    lsum += rs;

    // PV: A = V^T rows (m = d), B = P (n = t, k = s in C-layout regs)
#pragma unroll
    for (int sc = 0; sc < 4; ++sc) {
      int so = ((sc * 2 + (q >> 1)) ^ lx) * 16 + (q & 1) * 8;
#pragma unroll
      for (int dt = 0; dt < 4; ++dt) {
        s4v vv = *(const s4v*)(Vl + (dt * 16 + l) * 128 + so);
        O[dt] = __builtin_amdgcn_mfma_f32_16x16x16bf16_1k(vv, Pf[sc], O[dt], 0, 0, 0);
      }
    }
  };

  stage(0, lds[0]);
  __syncthreads();

  // main loop: tiles 0..qb-1 — no mask check, unconditional prefetch
  for (int j = 0; j < qb; ++j) {
    const char* Kl = lds[j & 1];
    stage(j + 1, lds[(j + 1) & 1]);
    tile_body(Kl, Kl + 8192, j, false);
    __syncthreads();  // staging of j+1 drained; all waves done with buf (j&1)
  }

  // peeled tail: tile qb — causal mask, no staging, no trailing barrier
  {
    const char* Kl = lds[qb & 1];
    tile_body(Kl, Kl + 8192, qb, true);
  }

  // epilogue: lane holds row t = tg, cols d = dt*16 + q*4 + r  -> float4 stores
  float inv = 1.f / lsum;
  int b = bh >> 4, h = bh & 15;
  float* ob = out + ((size_t)b * 2048 + tg) * 1024 + h * 64;
#pragma unroll
  for (int dt = 0; dt < 4; ++dt) {
    f4v val = O[dt] * inv;
    *(f4v*)(ob + dt * 16 + q * 4) = val;
  }
}

extern "C" void kernel_launch(void* const* d_in, const int* in_sizes, int n_in,
                              void* d_out, int out_size, void* d_ws, size_t ws_size,
                              hipStream_t stream) {
  const float* x = (const float*)d_in[0];     // [2,2048,1024]
  const float* W = (const float*)d_in[1];     // [1024,3072]
  const float* bias = (const float*)d_in[2];  // [3072]
  float* out = (float*)d_out;                 // [2,2048,1024]

  char* ws = (char*)d_ws;
  __hip_bfloat16* xb = (__hip_bfloat16*)ws;                    // 8,388,608 B
  __hip_bfloat16* Wt = (__hip_bfloat16*)(ws + 8388608);        // 6,291,456 B
  __hip_bfloat16* Qg = (__hip_bfloat16*)(ws + 14680064);       // 8,388,608 B
  __hip_bfloat16* Kg = (__hip_bfloat16*)(ws + 23068672);       // 8,388,608 B
  __hip_bfloat16* Vt = (__hip_bfloat16*)(ws + 31457280);       // 8,388,608 B

  k_prep<<<7168, 256, 0, stream>>>(x, W, xb, Wt);
  k_gemm<<<dim3(24, 32), 256, 0, stream>>>(xb, Wt, bias, Qg, Kg, Vt);
  k_attn<<<1024, 256, 0, stream>>>(Qg, Kg, Vt, out);
}